// Round 2
// baseline (760.819 us; speedup 1.0000x reference)
//
#include <hip/hip_runtime.h>
#include <stdint.h>

#define IN_DIM 32768
#define CLASSES 100
#define BATCH 4096
#define NPAD 112                   // 7 x 16 MFMA n-tiles
#define BK 32
#define MTILE 64
#define SPLITK 16
#define KCHUNK (IN_DIM / SPLITK)   // 2048
#define NSTEP (KCHUNK / BK)        // 64
#define MBLOCKS (BATCH / MTILE)    // 64
#define WTILE_ELEMS (NPAD * BK)    // 3584 shorts = 7168 B per k-step tile
#define WTILE_V8 (WTILE_ELEMS / 8) // 448 short8 fragments per tile
#define NTILES (SPLITK * NSTEP)    // 1024 tiles total in wp
#define WP_ELEMS (NPAD * IN_DIM)   // 3,670,016 shorts = 7.34 MB
#define PART_STRIDE (BATCH * NPAD) // floats per split-K slice
#define PART_OFF_BYTES (8u << 20)  // partials start 8 MB into ws (wp ends at 7.34 MB)

typedef __attribute__((ext_vector_type(8))) short short8;
typedef __attribute__((ext_vector_type(4))) float floatx4;

// fp32 -> bf16 round-to-nearest-even (bit trick; inputs are finite normals)
__device__ inline uint32_t f2bf(float f) {
  union { float f; uint32_t u; } v; v.f = f;
  uint32_t u = v.u;
  u += 0x7FFFu + ((u >> 16) & 1u);
  return u >> 16;
}
__device__ inline uint32_t pk(float a, float b) {
  return f2bf(a) | (f2bf(b) << 16);
}

// Pack sign(W) as bf16 {+1,-1,0} into wp, pre-swizzled into MFMA B-fragment
// order: tile = [kstep][ntile][kq][n][j] (ntile=c>>4, n=c&15, kq=(k>>3)&3, j=k&7).
// B-frag for (tile, ntile, lane) is the short8 at wp_v8[tile*448 + ntile*64 + lane]
// -> consecutive lanes read consecutive 16 B: perfectly coalesced dwordx4 loads,
// so the GEMM can consume B straight from global (L2-resident) with no LDS.
__global__ void pack_w_kernel(const float* __restrict__ W, short* __restrict__ wp) {
  int idx = blockIdx.x * 256 + threadIdx.x;      // [0, NPAD*IN_DIM)
  int c = idx >> 15;
  int kg = idx & (IN_DIM - 1);
  short val = 0;
  if (c < CLASSES) {
    float w = W[((size_t)c << 15) + kg];
    val = (w > 0.0f) ? (short)0x3F80 : ((w < 0.0f) ? (short)0xBF80 : (short)0);
  }
  int kstep = kg >> 5;
  int rem = kg & 31;
  int kq = rem >> 3;
  int j = rem & 7;
  int nt = c >> 4;
  int n = c & 15;
  wp[(size_t)kstep * WTILE_ELEMS + nt * 512 + kq * 128 + n * 8 + j] = val;
}

// GEMM: part[ks][m][c] = sum_{k in chunk ks} x[m][k] * signW[c][k]
// 1024 blocks (64 m-blocks x 16 split-K), 256 threads (4 waves), 4 blocks/CU.
// BARRIER-FREE: no LDS, no __syncthreads. Each wave owns 16 rows and free-runs
// its 64 k-steps. A-frags: per-lane 32B x loads (row lane&15, k quad*8), cvt to
// bf16 in-register, prefetched one iteration ahead (HBM latency). B-frags: per-
// lane 16B coalesced global loads from the pre-swizzled wp (L2/L3-resident;
// ~250cy L2 latency hidden by 4 waves/SIMD + counted vmcnt waits). This removes
// the per-k-step s_waitcnt vmcnt(0) barrier drain that serialized v1.
__global__ __launch_bounds__(256, 4) void gemm_kernel(const float* __restrict__ x,
                                                      const short* __restrict__ wp,
                                                      float* __restrict__ part) {
  const int tid = threadIdx.x;
  const int lane = tid & 63;
  const int w = tid >> 6;
  const int mb = blockIdx.x & (MBLOCKS - 1);
  const int ks = blockIdx.x >> 6;           // split-K index
  const int m_base = mb * MTILE;
  const int quad = lane >> 4;

  // A-source pointer for this lane: its row, its k-quad, within this K-chunk
  const float* xp = x + (size_t)(m_base + w * 16 + (lane & 15)) * IN_DIM
                      + ks * KCHUNK + quad * 8;
  // B-source: this lane's fragment slot in the first tile of this K-chunk
  const short8* wt = (const short8*)wp + (size_t)(ks * NSTEP) * WTILE_V8 + lane;

  floatx4 acc[7];
#pragma unroll
  for (int n = 0; n < 7; ++n) acc[n] = (floatx4)0.0f;

  // prologue: x tile 0 in registers
  floatx4 g0 = *(const floatx4*)xp;
  floatx4 g1 = *(const floatx4*)(xp + 4);

  for (int t = 0; t < NSTEP; ++t) {
    // --- issue x prefetch for tile t+1 (full HBM-latency ahead of use) ---
    int tn = (t + 1 < NSTEP) ? t + 1 : 0;              // dead on last iter
    const float* xn = xp + tn * BK;
    floatx4 h0 = *(const floatx4*)xn;
    floatx4 h1 = *(const floatx4*)(xn + 4);

    // --- build A fragment from prefetched x regs (tile t) ---
    short8 a;
    uint32_t* au = (uint32_t*)&a;
    au[0] = pk(g0.x, g0.y); au[1] = pk(g0.z, g0.w);
    au[2] = pk(g1.x, g1.y); au[3] = pk(g1.z, g1.w);

    // --- compute: 7 B-frags straight from global (L2), 7 MFMAs ---
    const short8* wb = wt + (size_t)t * WTILE_V8;
#pragma unroll
    for (int n = 0; n < 7; ++n) {
      short8 b = wb[n * 64];                           // coalesced 16B/lane
      acc[n] = __builtin_amdgcn_mfma_f32_16x16x32_bf16(a, b, acc[n], 0, 0, 0);
    }

    g0 = h0; g1 = h1;
  }

  // ---- epilogue: plain stores of partials (no atomics) ----
  // C layout: col = lane&15, row = quad*4 + r
  float* pr = part + (size_t)ks * PART_STRIDE;
  const int r0 = m_base + w * 16 + quad * 4;
  const int c16 = lane & 15;
#pragma unroll
  for (int n = 0; n < 7; ++n) {
    int col = n * 16 + c16;
#pragma unroll
    for (int r = 0; r < 4; ++r)
      pr[(size_t)(r0 + r) * NPAD + col] = acc[n][r];
  }
}

// out[b][c] = scale * sum_ks part[ks][b][c]
__global__ void reduce_kernel(const float* __restrict__ part, float* __restrict__ out) {
  int b = blockIdx.x;
  int c = threadIdx.x;
  if (c >= CLASSES) return;
  const float* p = part + (size_t)b * NPAD + c;
  float s = 0.0f;
#pragma unroll
  for (int ks = 0; ks < SPLITK; ++ks) s += p[(size_t)ks * PART_STRIDE];
  out[(size_t)b * CLASSES + c] = s * 0.005524271728019903f;   // 1/sqrt(32768)
}

extern "C" void kernel_launch(void* const* d_in, const int* in_sizes, int n_in,
                              void* d_out, int out_size, void* d_ws, size_t ws_size,
                              hipStream_t stream) {
  const float* x = (const float*)d_in[0];   // [4096, 32768] fp32
  const float* W = (const float*)d_in[1];   // [100, 32768] fp32
  float* out = (float*)d_out;               // [4096, 100] fp32
  short* wp = (short*)d_ws;                 // packed sign(W), 7.34 MB
  float* part = (float*)((char*)d_ws + PART_OFF_BYTES);  // 29.4 MB partials

  pack_w_kernel<<<WP_ELEMS / 256, 256, 0, stream>>>(W, wp);
  gemm_kernel<<<MBLOCKS * SPLITK, 256, 0, stream>>>(x, wp, part);
  reduce_kernel<<<BATCH, 128, 0, stream>>>(part, out);
}